// Round 1
// 627.225 us; speedup vs baseline: 1.0559x; 1.0559x over previous
//
#include <hip/hip_runtime.h>

#define B_CNT 4
#define N_CNT 10000
#define E_CNT 100000

typedef __attribute__((ext_vector_type(8))) short s16x8;
typedef __attribute__((ext_vector_type(4))) float f32x4;

__device__ __forceinline__ float b2f(unsigned short u) {
  union { unsigned int i; float f; } v; v.i = ((unsigned int)u) << 16; return v.f;
}
__device__ __forceinline__ unsigned short f2b(float f) {
  union { float f; unsigned int i; } v; v.f = f;
  unsigned int b = v.i;
  b += 0x7FFFu + ((b >> 16) & 1u);   // round-to-nearest-even
  return (unsigned short)(b >> 16);
}
__device__ __forceinline__ short f2bs(float f) { return (short)f2b(f); }

// ---------------------------------------------------------------------------
// K1: spectral transform (closed-form rfft/irfft over batch axis, n=4).
// ---------------------------------------------------------------------------
__global__ void k_fft(const float* __restrict__ x,
                      const float* __restrict__ tcwr,
                      const float* __restrict__ tcwi,
                      float* __restrict__ xnew) {
  __shared__ float Wr[256], Wi[256];
  const int t = threadIdx.x;
  Wr[t] = tcwr[t * 2] + tcwr[t * 2 + 1];
  Wi[t] = tcwi[t * 2] + tcwi[t * 2 + 1];
  __syncthreads();
  const int n = blockIdx.x * 256 + t;
  if (n >= N_CNT) return;

  float xt[4][16];
  for (int tt = 0; tt < 4; ++tt) {
    const float* xp = x + ((size_t)tt * N_CNT + n) * 16;
#pragma unroll
    for (int i0 = 0; i0 < 16; i0 += 4) {
      const float4 v = *(const float4*)(xp + i0);
      xt[tt][i0 + 0] = v.x; xt[tt][i0 + 1] = v.y;
      xt[tt][i0 + 2] = v.z; xt[tt][i0 + 3] = v.w;
    }
  }
  float s[16], a[16], bb[16];
#pragma unroll
  for (int i = 0; i < 16; ++i) {
    s[i]  = xt[0][i] + xt[1][i] + xt[2][i] + xt[3][i];
    a[i]  = xt[0][i] - xt[2][i];
    bb[i] = xt[1][i] - xt[3][i];
  }
  for (int o = 0; o < 16; ++o) {
    float r0 = 0.f, p = 0.f, qq = 0.f;
#pragma unroll
    for (int i = 0; i < 16; ++i) {
      const float wr = Wr[i * 16 + o], wi = Wi[i * 16 + o];
      r0 += s[i] * wr;
      p  += a[i] * wr + bb[i] * wi;
      qq += a[i] * wi - bb[i] * wr;
    }
    xnew[((size_t)0 * N_CNT + n) * 16 + o] = 0.25f * (r0 + 2.f * p);
    xnew[((size_t)1 * N_CNT + n) * 16 + o] = 0.25f * (r0 - 2.f * qq);
    xnew[((size_t)2 * N_CNT + n) * 16 + o] = 0.25f * (r0 - 2.f * p);
    xnew[((size_t)3 * N_CNT + n) * 16 + o] = 0.25f * (r0 + 2.f * qq);
  }
}

// ---------------------------------------------------------------------------
// K2: pack W1 (128x128) and W2 (128x384) fp32 -> bf16 MFMA B-fragment order.
// pw1 tile (nt,kk): lane l holds W[k=kk*32+(l>>4)*8+j][n=nt*16+(l&15)].
// pw2 w1-part (nt<16): col = nt*16+lm  (i=nt, o=lm).
// pw2 w2-part (nt>=16): col = 256 + (8*(lm&1)+(nt-16))*8 + (lm>>1)
//   => per thread, consecutive tiles give CONSECUTIVE i at fixed oo
//      (enables i-contiguous transposed EWt stores in the edge kernel).
// ---------------------------------------------------------------------------
__global__ void k_pack(const float* __restrict__ w1,
                       const float* __restrict__ w2,
                       unsigned short* __restrict__ pw1,
                       unsigned short* __restrict__ pw2) {
  const int t = blockIdx.x * 256 + threadIdx.x;  // 0..8191
  const int tile = t >> 6, l = t & 63, q = l >> 4, lm = l & 15;
  if (tile < 32) {
    const int nt = tile >> 2, kk = tile & 3;
    const int n = nt * 16 + lm;
    unsigned short* dst = pw1 + ((size_t)tile * 64 + l) * 8;
#pragma unroll
    for (int j = 0; j < 8; ++j) dst[j] = f2b(w1[(kk * 32 + q * 8 + j) * 128 + n]);
  } else {
    const int t2 = tile - 32;  // 0..95
    const int nt = t2 >> 2, kk = t2 & 3;
    int col;
    if (nt < 16) col = nt * 16 + lm;
    else col = 256 + (8 * (lm & 1) + (nt - 16)) * 8 + (lm >> 1);
    unsigned short* dst = pw2 + ((size_t)t2 * 64 + l) * 8;
#pragma unroll
    for (int j = 0; j < 8; ++j) dst[j] = f2b(w2[(kk * 32 + q * 8 + j) * 384 + col]);
  }
}

// ---------------------------------------------------------------------------
// K3: per-node in-degree histogram.
// ---------------------------------------------------------------------------
__global__ void k_cnt(const int* __restrict__ eidx, int* __restrict__ cnt) {
  const int e = blockIdx.x * 256 + threadIdx.x;
  if (e < E_CNT) atomicAdd(&cnt[eidx[E_CNT + e]], 1);
}

// ---------------------------------------------------------------------------
// K3b: exclusive prefix scan of cnt -> rowstart[10001], runoff copy.
// Single block, 256 threads, 40-element chunks.
// ---------------------------------------------------------------------------
__global__ void k_scan(const int* __restrict__ cnt, int* __restrict__ rowstart,
                       int* __restrict__ runoff) {
  __shared__ int partial[256];
  const int t = threadIdx.x;
  const int c0 = t * 40;
  int s = 0;
  for (int j = 0; j < 40; ++j) {
    const int idx = c0 + j;
    if (idx < N_CNT) s += cnt[idx];
  }
  partial[t] = s;
  __syncthreads();
  if (t == 0) {
    int acc = 0;
    for (int i = 0; i < 256; ++i) { const int v = partial[i]; partial[i] = acc; acc += v; }
  }
  __syncthreads();
  int acc = partial[t];
  for (int j = 0; j < 40; ++j) {
    const int idx = c0 + j;
    if (idx < N_CNT) { rowstart[idx] = acc; runoff[idx] = acc; acc += cnt[idx]; }
  }
  if (t == 255) rowstart[N_CNT] = acc;  // == E_CNT
}

// ---------------------------------------------------------------------------
// K3c: per-edge slot assignment within its dst group (CSR permutation).
// ---------------------------------------------------------------------------
__global__ void k_pos(const int* __restrict__ eidx, int* __restrict__ runoff,
                      int* __restrict__ pos) {
  const int e = blockIdx.x * 256 + threadIdx.x;
  if (e < E_CNT) pos[e] = atomicAdd(&runoff[eidx[E_CNT + e]], 1);
}

// ---------------------------------------------------------------------------
// K4: fused edge kernel. Per block: 32 edges, one batch.
//   GEMM1: H(32x128) = relu(EA @ W1 + b1)    (MFMA, A-loads hoisted to regs)
//   GEMM2: EW(32x384) = H @ W2 + b2          (MFMA, A from LDS)
//   EW stored TRANSPOSED in LDS: EWt[edge][ch 0..23][i 0..15] (i contiguous),
//   ch<16 = w1 output o, ch>=16 = 16+oo.
//   messages: 24 dots/edge (3 per thread), b128 LDS reads,
//   sink: plain store to msgbuf[b][pos[e]][40] (CSR) or atomicAdd (fallback).
// LDS 36,992 B -> 4 blocks/CU; __launch_bounds__(256,4) -> 128 VGPR budget.
// ---------------------------------------------------------------------------
template <bool ATOMIC>
__global__ __launch_bounds__(256, 4) void k_edge(
    const float* __restrict__ ea, const int* __restrict__ eidx,
    const float* __restrict__ esh,
    const unsigned short* __restrict__ pw1, const unsigned short* __restrict__ pw2,
    const float* __restrict__ b1v, const float* __restrict__ b2v,
    const float* __restrict__ xnew, const int* __restrict__ idx_arr,
    float* __restrict__ out_base, const size_t bstride) {
  __shared__ __align__(16) unsigned short Hs[32 * 136];   // [edge][k], +8 pad
  __shared__ __align__(16) unsigned short EWt[32 * 392];  // [edge][24ch][16i], +8 pad
  __shared__ float xgs[32 * 20];                          // 16 + 4 pad
  __shared__ float shs[32 * 4];
  __shared__ int ids[32];

  const int t = threadIdx.x;
  const int b = blockIdx.y;
  const int e0 = blockIdx.x * 32;
  const int w = t >> 6, l = t & 63, q = l >> 4, lm = l & 15;

  // ---- phase 0: stage xg (gather), sh, row ids ----
  if (t < 128) {
    const int el = t >> 2, i0 = (t & 3) * 4;
    const int src = eidx[e0 + el];
    const float4 v = *(const float4*)(xnew + ((size_t)b * N_CNT + src) * 16 + i0);
    xgs[el * 20 + i0 + 0] = v.x;
    xgs[el * 20 + i0 + 1] = v.y;
    xgs[el * 20 + i0 + 2] = v.z;
    xgs[el * 20 + i0 + 3] = v.w;
  } else if (t < 160) {
    const int el = t - 128;
    const float4 v = *(const float4*)(esh + ((size_t)b * E_CNT + e0 + el) * 4);
    shs[el * 4 + 0] = v.x;
    shs[el * 4 + 1] = v.y;
    shs[el * 4 + 2] = v.z;
    shs[el * 4 + 3] = v.w;
  } else if (t < 192) {
    const int el = t - 160;
    ids[el] = idx_arr[e0 + el];
  }

  // ---- GEMM1: hoist all 16 A-loads, then convert+MFMA ----
  f32x4 acc1[2][2];
#pragma unroll
  for (int mt = 0; mt < 2; ++mt)
#pragma unroll
    for (int j = 0; j < 2; ++j) acc1[mt][j] = (f32x4)0.0f;

  const float* eab = ea + (size_t)b * E_CNT * 128;
  float4 araw[4][2][2];
#pragma unroll
  for (int kk = 0; kk < 4; ++kk)
#pragma unroll
    for (int mt = 0; mt < 2; ++mt) {
      const float* ap = eab + ((size_t)(e0 + mt * 16 + lm)) * 128 + kk * 32 + q * 8;
      araw[kk][mt][0] = *(const float4*)ap;
      araw[kk][mt][1] = *(const float4*)(ap + 4);
    }
#pragma unroll
  for (int kk = 0; kk < 4; ++kk) {
    const s16x8 bf0 = *(const s16x8*)(pw1 + (((size_t)(2 * w + 0) * 4 + kk) * 64 + l) * 8);
    const s16x8 bf1 = *(const s16x8*)(pw1 + (((size_t)(2 * w + 1) * 4 + kk) * 64 + l) * 8);
#pragma unroll
    for (int mt = 0; mt < 2; ++mt) {
      const float4 a0 = araw[kk][mt][0];
      const float4 a1 = araw[kk][mt][1];
      const s16x8 af = { f2bs(a0.x), f2bs(a0.y), f2bs(a0.z), f2bs(a0.w),
                         f2bs(a1.x), f2bs(a1.y), f2bs(a1.z), f2bs(a1.w) };
      acc1[mt][0] = __builtin_amdgcn_mfma_f32_16x16x32_bf16(af, bf0, acc1[mt][0], 0, 0, 0);
      acc1[mt][1] = __builtin_amdgcn_mfma_f32_16x16x32_bf16(af, bf1, acc1[mt][1], 0, 0, 0);
    }
  }
#pragma unroll
  for (int j = 0; j < 2; ++j) {
    const int n = (2 * w + j) * 16 + lm;
    const float bias = b1v[n];
#pragma unroll
    for (int mt = 0; mt < 2; ++mt)
#pragma unroll
      for (int r = 0; r < 4; ++r) {
        float v = acc1[mt][j][r] + bias;
        v = fmaxf(v, 0.0f);
        Hs[(mt * 16 + q * 4 + r) * 136 + n] = f2b(v);
      }
  }

  // prefetch GEMM2 B-fragments for kk=0 BEFORE the barrier (independent of Hs)
  s16x8 bw0[6];
#pragma unroll
  for (int jj = 0; jj < 6; ++jj)
    bw0[jj] = *(const s16x8*)(pw2 + (((size_t)(6 * w + jj) * 4 + 0) * 64 + l) * 8);
  __syncthreads();

  // ---- GEMM2 ----
  f32x4 acc2[2][6];
#pragma unroll
  for (int mt = 0; mt < 2; ++mt)
#pragma unroll
    for (int jj = 0; jj < 6; ++jj) acc2[mt][jj] = (f32x4)0.0f;

#pragma unroll
  for (int kk = 0; kk < 4; ++kk) {
    s16x8 bw[6];
    if (kk == 0) {
#pragma unroll
      for (int jj = 0; jj < 6; ++jj) bw[jj] = bw0[jj];
    } else {
#pragma unroll
      for (int jj = 0; jj < 6; ++jj)
        bw[jj] = *(const s16x8*)(pw2 + (((size_t)(6 * w + jj) * 4 + kk) * 64 + l) * 8);
    }
#pragma unroll
    for (int mt = 0; mt < 2; ++mt) {
      const s16x8 ah = *(const s16x8*)(&Hs[(mt * 16 + lm) * 136 + kk * 32 + q * 8]);
#pragma unroll
      for (int jj = 0; jj < 6; ++jj)
        acc2[mt][jj] = __builtin_amdgcn_mfma_f32_16x16x32_bf16(ah, bw[jj], acc2[mt][jj], 0, 0, 0);
    }
  }

  // ---- epilogue 2: bias + bf16, TRANSPOSED pair-packed b32 stores ----
  // wave w tile T=6w+jj: T<16 -> (ch=lm, i=T); T>=16 -> (ch=16+(lm>>1), i=8*(l&1)+T-16)
  float bias6[6];
#pragma unroll
  for (int jj = 0; jj < 6; ++jj) {
    const int T = 6 * w + jj;
    const int bcol = (T < 16) ? (T * 16 + lm)
                              : (256 + (8 * (l & 1) + (T - 16)) * 8 + (lm >> 1));
    bias6[jj] = b2v[bcol];
  }
#pragma unroll
  for (int mt = 0; mt < 2; ++mt)
#pragma unroll
    for (int r = 0; r < 4; ++r) {
      const int edge = mt * 16 + q * 4 + r;
      unsigned short u[6];
#pragma unroll
      for (int jj = 0; jj < 6; ++jj) u[jj] = f2b(acc2[mt][jj][r] + bias6[jj]);
      const unsigned int p0 = (unsigned int)u[0] | ((unsigned int)u[1] << 16);
      const unsigned int p1 = (unsigned int)u[2] | ((unsigned int)u[3] << 16);
      const unsigned int p2 = (unsigned int)u[4] | ((unsigned int)u[5] << 16);
      unsigned int* base = (unsigned int*)&EWt[edge * 392];
      if (w < 2) {                       // i = 6w..6w+5, ch = lm
        unsigned int* d = base + lm * 8 + 3 * w;
        d[0] = p0; d[1] = p1; d[2] = p2;
      } else if (w == 2) {               // i = 12..15 at ch=lm; i=8a,8a+1 at ch2
        unsigned int* d = base + lm * 8 + 6;
        d[0] = p0; d[1] = p1;
        base[(16 + (lm >> 1)) * 8 + 4 * (l & 1)] = p2;
      } else {                           // i = 8a+2..8a+7 at ch2
        unsigned int* d = base + (16 + (lm >> 1)) * 8 + 4 * (l & 1) + 1;
        d[0] = p0; d[1] = p1; d[2] = p2;
      }
    }
  __syncthreads();

  // ---- phase 3: 24 dots/edge, 3 per thread, b128 LDS reads ----
  {
    const int m = t >> 3, sub = t & 7;
    float xr[16];
#pragma unroll
    for (int i0 = 0; i0 < 16; i0 += 4) {
      const float4 v = *(const float4*)&xgs[m * 20 + i0];
      xr[i0] = v.x; xr[i0 + 1] = v.y; xr[i0 + 2] = v.z; xr[i0 + 3] = v.w;
    }
    const float sh0v = 0.25f * shs[m * 4 + 0];   // ALPHA = 1/sqrt(16)
    const float s1a = 0.25f * shs[m * 4 + 1];
    const float s1b = 0.25f * shs[m * 4 + 2];
    const float s1c = 0.25f * shs[m * 4 + 3];
    float* outp = out_base + (size_t)b * bstride + (size_t)ids[m] * 40;
#pragma unroll
    for (int dd = 0; dd < 3; ++dd) {
      const int d = sub * 3 + dd;                // 0..23 == EWt channel
      const unsigned short* ep = &EWt[m * 392 + d * 16];
      const s16x8 eA = *(const s16x8*)ep;
      const s16x8 eB = *(const s16x8*)(ep + 8);
      float dotv = 0.f;
#pragma unroll
      for (int i = 0; i < 8; ++i) {
        dotv += xr[i] * b2f((unsigned short)eA[i]);
        dotv += xr[8 + i] * b2f((unsigned short)eB[i]);
      }
      if (d < 16) {
        const float val = dotv * sh0v;
        if (ATOMIC) atomicAdd(outp + d, val); else outp[d] = val;
      } else {
        const int c0 = 16 + (d - 16) * 3;
        if (ATOMIC) {
          atomicAdd(outp + c0 + 0, dotv * s1a);
          atomicAdd(outp + c0 + 1, dotv * s1b);
          atomicAdd(outp + c0 + 2, dotv * s1c);
        } else {
          outp[c0 + 0] = dotv * s1a;
          outp[c0 + 1] = dotv * s1b;
          outp[c0 + 2] = dotv * s1c;
        }
      }
    }
  }
}

// ---------------------------------------------------------------------------
// K5 (fallback only): agg = sums / max(cnt,1) + per-channel partials.
// ---------------------------------------------------------------------------
__global__ void k_agg(float* __restrict__ sums, const int* __restrict__ cnt,
                      float* __restrict__ psum, float* __restrict__ psq) {
  __shared__ float ls[40], lq[40];
  const int t = threadIdx.x;
  if (t < 40) { ls[t] = 0.f; lq[t] = 0.f; }
  __syncthreads();
  const unsigned base = blockIdx.x * 2048u + t;
  for (int k2 = 0; k2 < 8; ++k2) {
    const unsigned idx = base + k2 * 256u;
    if (idx < 1600000u) {
      const unsigned row = idx / 40u;
      const unsigned node = row % 10000u;
      const float c = (float)cnt[node];
      const float v = sums[idx] / fmaxf(c, 1.f);
      sums[idx] = v;
      const unsigned ch = idx - row * 40u;
      atomicAdd(&ls[ch], v);
      atomicAdd(&lq[ch], v * v);
    }
  }
  __syncthreads();
  if (t < 40) {
    atomicAdd(&psum[t], ls[t]);
    atomicAdd(&psq[t], lq[t]);
  }
}

// ---------------------------------------------------------------------------
// K5b (CSR): gather rows per (b,node), mean-divide, BN partials.
// One wave per 16 (b,node) pairs; lanes = channels (40 of 64 active).
// ---------------------------------------------------------------------------
__global__ __launch_bounds__(256) void k_gather(
    const float* __restrict__ msgbuf, const int* __restrict__ rowstart,
    float* __restrict__ sums, float* __restrict__ psum, float* __restrict__ psq) {
  const int t = threadIdx.x;
  const int wid = t >> 6, ch = t & 63;
  float lsum = 0.f, lsq = 0.f;
  for (int k = 0; k < 16; ++k) {
    const int p = blockIdx.x * 64 + wid * 16 + k;   // 0..39999 = b*10000+node
    const int bb = p / 10000;
    const int node = p - bb * 10000;
    const int r0 = rowstart[node], r1 = rowstart[node + 1];
    if (ch < 40) {
      float v = 0.f;
      for (int r = r0; r < r1; ++r) v += msgbuf[((size_t)bb * E_CNT + r) * 40 + ch];
      v /= fmaxf((float)(r1 - r0), 1.f);
      sums[(size_t)p * 40 + ch] = v;
      lsum += v; lsq += v * v;
    }
  }
  if (ch < 40) {
    atomicAdd(&psum[ch], lsum);
    atomicAdd(&psq[ch], lsq);
  }
}

// ---------------------------------------------------------------------------
// K6: finalize BN scale/shift.
// ---------------------------------------------------------------------------
__global__ void k_stats(const float* __restrict__ psum, const float* __restrict__ psq,
                        const float* __restrict__ gma, const float* __restrict__ bta,
                        float* __restrict__ scalev, float* __restrict__ shiftv) {
  const int t = threadIdx.x;
  if (t < 40) {
    const float inv = 1.0f / 40000.0f;  // B*N rows
    const float mu = psum[t] * inv;
    const float var = psq[t] * inv - mu * mu;
    const float sc = rsqrtf(fmaxf(var, 0.0f) + 1e-5f) * gma[t];
    scalev[t] = sc;
    shiftv[t] = bta[t] - mu * sc;
  }
}

// ---------------------------------------------------------------------------
// K7: normalize + fp32 output.
// ---------------------------------------------------------------------------
__global__ void k_out(const float* __restrict__ agg, const float* __restrict__ scalev,
                      const float* __restrict__ shiftv, float* __restrict__ outp) {
  __shared__ float sc[40], sh[40];
  const int t = threadIdx.x;
  if (t < 40) { sc[t] = scalev[t]; sh[t] = shiftv[t]; }
  __syncthreads();
  const unsigned base = blockIdx.x * 1024u + t;
#pragma unroll
  for (int k2 = 0; k2 < 4; ++k2) {
    const unsigned idx = base + k2 * 256u;
    if (idx < 1600000u) {
      const unsigned row = idx / 40u;
      const unsigned ch = idx - row * 40u;
      outp[idx] = agg[idx] * sc[ch] + sh[ch];
    }
  }
}

// ---------------------------------------------------------------------------
// Workspace layout (bytes):
//   [0)          sums      6,400,000   (CSR: written by k_gather; FB: zeroed)
//   [6,400,000)  cnt          40,000   (zeroed)
//   [6,440,000)  psum            160   (zeroed)
//   [6,440,160)  psq             160   (zeroed)
//   [6,440,448)  xnew      2,560,000
//   [9,000,448)  pw1          32,768
//   [9,033,216)  pw2          98,304
//   [9,131,520)  scale           160
//   [9,131,680)  shift           160
//   [9,131,840)  rowstart     40,016   (10001 ints)           } CSR only
//   [9,171,856)  runoff       40,000                          }
//   [9,211,856)  pos         400,000                          }
//   [9,611,904)  msgbuf   64,000,000                          }
// CSR total 73,611,904; fallback total ~9.13 MB
// ---------------------------------------------------------------------------
extern "C" void kernel_launch(void* const* d_in, const int* in_sizes, int n_in,
                              void* d_out, int out_size, void* d_ws, size_t ws_size,
                              hipStream_t stream) {
  (void)in_sizes; (void)n_in; (void)out_size;
  const float* x    = (const float*)d_in[0];
  const int*   eidx = (const int*)d_in[1];
  const float* ea   = (const float*)d_in[2];
  const float* esh  = (const float*)d_in[3];
  const float* tcwr = (const float*)d_in[4];
  const float* tcwi = (const float*)d_in[5];
  const float* w1   = (const float*)d_in[6];
  const float* b1   = (const float*)d_in[7];
  const float* w2   = (const float*)d_in[8];
  const float* b2   = (const float*)d_in[9];
  const float* gma  = (const float*)d_in[10];
  const float* bta  = (const float*)d_in[11];

  char* ws = (char*)d_ws;
  float*          sums     = (float*)(ws + 0);
  int*            cnt      = (int*)(ws + 6400000);
  float*          psum     = (float*)(ws + 6440000);
  float*          psq      = (float*)(ws + 6440160);
  float*          xnew     = (float*)(ws + 6440448);
  unsigned short* pw1      = (unsigned short*)(ws + 9000448);
  unsigned short* pw2      = (unsigned short*)(ws + 9033216);
  float*          scalev   = (float*)(ws + 9131520);
  float*          shiftv   = (float*)(ws + 9131680);
  int*            rowstart = (int*)(ws + 9131840);
  int*            runoff   = (int*)(ws + 9171856);
  int*            pos      = (int*)(ws + 9211856);
  float*          msgbuf   = (float*)(ws + 9611904);

  const bool use_csr = ws_size >= (size_t)73611904;

  if (use_csr) {
    hipMemsetAsync(ws + 6400000, 0, 40320, stream);  // cnt + psum + psq
    k_fft<<<dim3(40), dim3(256), 0, stream>>>(x, tcwr, tcwi, xnew);
    k_pack<<<dim3(32), dim3(256), 0, stream>>>(w1, w2, pw1, pw2);
    k_cnt<<<dim3(391), dim3(256), 0, stream>>>(eidx, cnt);
    k_scan<<<dim3(1), dim3(256), 0, stream>>>(cnt, rowstart, runoff);
    k_pos<<<dim3(391), dim3(256), 0, stream>>>(eidx, runoff, pos);
    k_edge<false><<<dim3(E_CNT / 32, B_CNT), dim3(256), 0, stream>>>(
        ea, eidx, esh, pw1, pw2, b1, b2, xnew, pos, msgbuf, (size_t)E_CNT * 40);
    k_gather<<<dim3(625), dim3(256), 0, stream>>>(msgbuf, rowstart, sums, psum, psq);
    k_stats<<<dim3(1), dim3(64), 0, stream>>>(psum, psq, gma, bta, scalev, shiftv);
    k_out<<<dim3(1563), dim3(256), 0, stream>>>(sums, scalev, shiftv, (float*)d_out);
  } else {
    hipMemsetAsync(ws, 0, 6440320, stream);
    k_fft<<<dim3(40), dim3(256), 0, stream>>>(x, tcwr, tcwi, xnew);
    k_pack<<<dim3(32), dim3(256), 0, stream>>>(w1, w2, pw1, pw2);
    k_cnt<<<dim3(391), dim3(256), 0, stream>>>(eidx, cnt);
    k_edge<true><<<dim3(E_CNT / 32, B_CNT), dim3(256), 0, stream>>>(
        ea, eidx, esh, pw1, pw2, b1, b2, xnew, eidx + E_CNT, sums, (size_t)N_CNT * 40);
    k_agg<<<dim3(782), dim3(256), 0, stream>>>(sums, cnt, psum, psq);
    k_stats<<<dim3(1), dim3(64), 0, stream>>>(psum, psq, gma, bta, scalev, shiftv);
    k_out<<<dim3(1563), dim3(256), 0, stream>>>(sums, scalev, shiftv, (float*)d_out);
  }
}